// Round 1
// baseline (152.632 us; speedup 1.0000x reference)
//
#include <hip/hip_runtime.h>
#include <hip/hip_fp16.h>
#include <stdint.h>

// out[16384,1024] = fp16(x) @ (fp16(sparsify24(fp16(W))) * scale -> fp16) + bias
#define M_TOT 16384
#define N_TOT 1024
#define K_TOT 1024

typedef _Float16 f16x8 __attribute__((ext_vector_type(8)));
typedef float f32x4 __attribute__((ext_vector_type(4)));
typedef unsigned short ushort4v __attribute__((ext_vector_type(4)));

// async global->LDS DMA, 16B per lane. LDS dest must be wave-uniform base + lane*16.
__device__ inline void gl2lds16(const void* g, void* l) {
    __builtin_amdgcn_global_load_lds(
        (const __attribute__((address_space(1))) void*)(uintptr_t)(g),
        (__attribute__((address_space(3))) void*)(uint32_t)(uintptr_t)(l),
        16, 0, 0);
}

// --- Kernel 1 (fused): blocks [0,256) do weight prep; blocks [256, 256+8192) cast x.
__global__ void __launch_bounds__(256) prep_and_cast(const float* __restrict__ X,
                                                     const float* __restrict__ W,
                                                     const float* __restrict__ scale_p,
                                                     _Float16* __restrict__ Xh,
                                                     _Float16* __restrict__ wT) {
    const int tid = threadIdx.x;
    if (blockIdx.x < 256) {
        // W[K][N] fp32 -> fp16 -> 2:4 sparsify along N (groups of 4) * scale -> wT[N][K] fp16
        __shared__ _Float16 sT[64 * 68 + 4];   // sT[n][k], stride 68 (pad)
        const float scale = scale_p[0];
        const int k0 = (blockIdx.x & 15) * 64;
        const int n0 = (blockIdx.x >> 4) * 64;
        const int r = tid >> 4;            // 0..15
        const int c4 = (tid & 15) * 4;     // 0..60: one 2:4 group = one float4
#pragma unroll
        for (int p = 0; p < 4; ++p) {
            const int k = p * 16 + r;
            float4 w4 = *(const float4*)&W[(size_t)(k0 + k) * N_TOT + n0 + c4];
            _Float16 h0 = (_Float16)w4.x, h1 = (_Float16)w4.y, h2 = (_Float16)w4.z, h3 = (_Float16)w4.w;
            float a0 = fabsf((float)h0), a1 = fabsf((float)h1), a2 = fabsf((float)h2), a3 = fabsf((float)h3);
            float lo01 = fminf(a0, a1), hi01 = fmaxf(a0, a1);
            float lo23 = fminf(a2, a3), hi23 = fmaxf(a2, a3);
            float s2 = fmaxf(fminf(hi01, hi23), fmaxf(lo01, lo23));
            sT[(c4 + 0) * 68 + k] = (_Float16)(((a0 >= s2) ? (float)h0 : 0.0f) * scale);
            sT[(c4 + 1) * 68 + k] = (_Float16)(((a1 >= s2) ? (float)h1 : 0.0f) * scale);
            sT[(c4 + 2) * 68 + k] = (_Float16)(((a2 >= s2) ? (float)h2 : 0.0f) * scale);
            sT[(c4 + 3) * 68 + k] = (_Float16)(((a3 >= s2) ? (float)h3 : 0.0f) * scale);
        }
        __syncthreads();
#pragma unroll
        for (int p = 0; p < 4; ++p) {
            const int n = p * 16 + r;
            ushort4v v = *(const ushort4v*)&sT[n * 68 + c4];
            *(ushort4v*)&wT[(size_t)(n0 + n) * K_TOT + k0 + c4] = v;
        }
    } else {
        size_t i = ((size_t)(blockIdx.x - 256) * 256 + tid) * 8;
        float4 x0 = *(const float4*)&X[i];
        float4 x1 = *(const float4*)&X[i + 4];
        f16x8 h;
        h[0] = (_Float16)x0.x; h[1] = (_Float16)x0.y; h[2] = (_Float16)x0.z; h[3] = (_Float16)x0.w;
        h[4] = (_Float16)x1.x; h[5] = (_Float16)x1.y; h[6] = (_Float16)x1.z; h[7] = (_Float16)x1.w;
        *(f16x8*)&Xh[i] = h;
    }
}

// --- Kernel 2: 256x256 8-phase counted-vmcnt GEMM (T2 swizzle + T3/T4 pipeline + T5 setprio).
// C = A[M][K] * Bt[N][K]^T + bias. 512 threads = 8 waves (2M x 4N), per-wave 128x64 out.
// BK=64 as two K-halves of 32. LDS 128 KiB: [buf][khalf][256 rows][32], double-buffered.
// Swizzle: 16B slot s of each 64B row holds global k-group g = s ^ ((row>>1)&3); applied
// on the GLOBAL source (gl2lds dest stays linear) and inverted on the ds_read side ->
// 8 distinct banks x 2 lanes per 16-lane group = conflict-free.
// Schedule per iter (2 K-tiles): 8 phases, each {ds_read frag, stage 1 half-tile,
// s_barrier, 16 MFMA (setprio 1), s_barrier}; s_waitcnt vmcnt(8) at even phases only
// (12 half-tile loads in flight, never drained to 0). Derived-wait check:
//   end ph8 completes T(2i+2) A0,B0 (read ph1,2) ... end ph6 completes A1,B1 (read ph7,8).
// Grid 256 blocks = 1 block/CU exact; by = id&63 -> 4 blocks sharing an A-panel on one XCD.
__global__ void __launch_bounds__(512, 2) gemm_bt(const _Float16* __restrict__ A,
                                                  const _Float16* __restrict__ Bt,
                                                  const float* __restrict__ bias,
                                                  float* __restrict__ C) {
    __shared__ __align__(16) _Float16 sA[2][2][256 * 32];   // [buf][khalf][row*32+col]
    __shared__ __align__(16) _Float16 sB[2][2][256 * 32];

    const int tid = threadIdx.x;
    const int id = blockIdx.x;
    const int by = id & 63;             // M tile 0..63 (by%8 = XCD)
    const int bx = id >> 6;             // N tile 0..3
    const int wave = tid >> 6;
    const int lane = tid & 63;
    const int wm = wave >> 2;           // 0..1 -> M half (128 rows)
    const int wn = wave & 3;            // 0..3 -> N quarter (64 cols)
    const int quad = lane >> 4;
    const int l16 = lane & 15;

    // staging: 512 threads cover 128 rows x 64B per round; 2 rounds per 256x32 half-tile
    const int row0 = tid >> 2;          // 0..127
    const int s4 = tid & 3;             // 16B slot within row
    const int g = s4 ^ ((row0 >> 1) & 3);   // pre-swizzled global k-group (same for row0+128)
    const _Float16* gA = A + (size_t)(by * 256 + row0) * K_TOT + g * 8;
    const _Float16* gB = Bt + (size_t)(bx * 256 + row0) * K_TOT + g * 8;
    const int dst0 = row0 * 32 + s4 * 8;    // LDS dest elem off; byte off == tid*16 (DMA-legal)

    // ds_read side: slot = quad ^ ((row>>1)&3); row = 16*R + l16 with R aligned -> lane-const
    const int rdoff = l16 * 64 + ((quad ^ ((l16 >> 1) & 3)) << 4);   // bytes

    f32x4 acc[8][4];
#pragma unroll
    for (int i = 0; i < 8; ++i)
#pragma unroll
        for (int j = 0; j < 4; ++j)
            acc[i][j] = (f32x4){0.f, 0.f, 0.f, 0.f};
    f16x8 fa[4], fb[4];

#define STAGE_A(b, kt, kh) do {                                            \
        const _Float16* s_ = gA + (kt) * 64 + (kh) * 32;                   \
        gl2lds16(s_, &sA[b][kh][dst0]);                                    \
        gl2lds16(s_ + (size_t)128 * K_TOT, &sA[b][kh][dst0 + 128 * 32]);   \
    } while (0)
#define STAGE_B(b, kt, kh) do {                                            \
        const _Float16* s_ = gB + (kt) * 64 + (kh) * 32;                   \
        gl2lds16(s_, &sB[b][kh][dst0]);                                    \
        gl2lds16(s_ + (size_t)128 * K_TOT, &sB[b][kh][dst0 + 128 * 32]);   \
    } while (0)
#define FENCE asm volatile("" ::: "memory")
#define WAIT8 asm volatile("s_waitcnt vmcnt(8)" ::: "memory")
#define BAR do { FENCE; __builtin_amdgcn_s_barrier(); FENCE; } while (0)

    // phase: {frag ds_reads, stage issue} | barrier | setprio(1) 16xMFMA setprio(0)
#define PHASE(b, ks, qm, LOADB, STAGE_STMT) do {                                   \
        {                                                                          \
            const char* bA_ = (const char*)&sA[b][ks][0] + rdoff + wm * 8192 + (qm) * 4096; \
            fa[0] = *(const f16x8*)(bA_);                                          \
            fa[1] = *(const f16x8*)(bA_ + 1024);                                   \
            fa[2] = *(const f16x8*)(bA_ + 2048);                                   \
            fa[3] = *(const f16x8*)(bA_ + 3072);                                   \
            if (LOADB) {                                                           \
                const char* bB_ = (const char*)&sB[b][ks][0] + rdoff + wn * 4096;  \
                fb[0] = *(const f16x8*)(bB_);                                      \
                fb[1] = *(const f16x8*)(bB_ + 1024);                               \
                fb[2] = *(const f16x8*)(bB_ + 2048);                               \
                fb[3] = *(const f16x8*)(bB_ + 3072);                               \
            }                                                                      \
        }                                                                          \
        STAGE_STMT;                                                                \
        BAR;                                                                       \
        __builtin_amdgcn_s_setprio(1);                                             \
        _Pragma("unroll")                                                          \
        for (int ii = 0; ii < 4; ++ii) {                                           \
            _Pragma("unroll")                                                      \
            for (int j = 0; j < 4; ++j)                                            \
                acc[(qm) * 4 + ii][j] = __builtin_amdgcn_mfma_f32_16x16x32_f16(    \
                    fa[ii], fb[j], acc[(qm) * 4 + ii][j], 0, 0, 0);                \
        }                                                                          \
        __builtin_amdgcn_s_setprio(0);                                             \
    } while (0)

    // prologue: T0 complete + T1 K-half0 (12 loads); wait oldest 4 (T0 Kh0) -> 8 in flight
    STAGE_A(0, 0, 0); STAGE_B(0, 0, 0);
    STAGE_A(0, 0, 1); STAGE_B(0, 0, 1);
    STAGE_A(1, 1, 0); STAGE_B(1, 1, 0);
    WAIT8;
    BAR;

    for (int it = 0; it < 8; ++it) {
        const int t1 = (2 * it + 1) & 15;   // buf1's current tile (finish its Kh1)
        const int t2 = (2 * it + 2) & 15;   // buf0's next tile (t=7 wraps harmlessly)
        const int t3 = (2 * it + 3) & 15;   // buf1's next tile (first half)
        PHASE(0, 0, 0, 1, STAGE_A(1, t1, 1));        BAR;   // ph1
        PHASE(0, 0, 1, 0, STAGE_B(1, t1, 1)); WAIT8; BAR;   // ph2 -> completes T(2i)A1,B1
        PHASE(0, 1, 0, 1, STAGE_A(0, t2, 0));        BAR;   // ph3
        PHASE(0, 1, 1, 0, STAGE_B(0, t2, 0)); WAIT8; BAR;   // ph4 -> completes T(2i+1)A0,B0
        PHASE(1, 0, 0, 1, STAGE_A(0, t2, 1));        BAR;   // ph5
        PHASE(1, 0, 1, 0, STAGE_B(0, t2, 1)); WAIT8; BAR;   // ph6 -> completes T(2i+1)A1,B1
        PHASE(1, 1, 0, 1, STAGE_A(1, t3, 0));        BAR;   // ph7
        PHASE(1, 1, 1, 0, STAGE_B(1, t3, 0)); WAIT8; BAR;   // ph8 -> completes T(2i+2)A0,B0
    }

    // epilogue: D row = quad*4 + r (M), col = l16 (N) per 16x16 frag; bias add, plain stores
#pragma unroll
    for (int j = 0; j < 4; ++j) {
        const int col = bx * 256 + wn * 64 + j * 16 + l16;
        const float bj = bias[col];
#pragma unroll
        for (int mi = 0; mi < 8; ++mi) {
            const int row0o = by * 256 + wm * 128 + mi * 16 + quad * 4;
#pragma unroll
            for (int r = 0; r < 4; ++r) {
                C[(size_t)(row0o + r) * N_TOT + col] = acc[mi][j][r] + bj;
            }
        }
    }

#undef PHASE
#undef BAR
#undef WAIT8
#undef FENCE
#undef STAGE_B
#undef STAGE_A
}

extern "C" void kernel_launch(void* const* d_in, const int* in_sizes, int n_in,
                              void* d_out, int out_size, void* d_ws, size_t ws_size,
                              hipStream_t stream) {
    const float* x      = (const float*)d_in[0];   // [4,4096,1024] fp32
    const float* weight = (const float*)d_in[1];   // [1024,1024] fp32
    const float* bias   = (const float*)d_in[2];   // [1024] fp32
    const float* sscale = (const float*)d_in[3];   // [1] fp32
    float* out = (float*)d_out;

    _Float16* wT = (_Float16*)d_ws;                                    // 2 MiB
    _Float16* xh = (_Float16*)((char*)d_ws + (size_t)2 * 1024 * 1024); // 32 MiB

    prep_and_cast<<<256 + (M_TOT * K_TOT / 8) / 256, 256, 0, stream>>>(x, weight, sscale, xh, wT);
    gemm_bt<<<256, 512, 0, stream>>>(xh, wT, bias, out);
}

// Round 3
// 152.040 us; speedup vs baseline: 1.0039x; 1.0039x over previous
//
#include <hip/hip_runtime.h>
#include <hip/hip_fp16.h>
#include <stdint.h>

// out[16384,1024] = fp16(x) @ (fp16(sparsify24(fp16(W))) * scale -> fp16) + bias
#define M_TOT 16384
#define N_TOT 1024
#define K_TOT 1024

typedef _Float16 f16x8 __attribute__((ext_vector_type(8)));
typedef float f32x4 __attribute__((ext_vector_type(4)));
typedef unsigned short ushort4v __attribute__((ext_vector_type(4)));

// async global->LDS DMA, 16B per lane. LDS dest must be wave-uniform base + lane*16.
__device__ inline void gl2lds16(const void* g, void* l) {
    __builtin_amdgcn_global_load_lds(
        (const __attribute__((address_space(1))) void*)(uintptr_t)(g),
        (__attribute__((address_space(3))) void*)(uint32_t)(uintptr_t)(l),
        16, 0, 0);
}

// --- Kernel 1 (fused, verified r0/r1): blocks [0,256) weight prep; rest cast x->fp16.
__global__ void __launch_bounds__(256) prep_and_cast(const float* __restrict__ X,
                                                     const float* __restrict__ W,
                                                     const float* __restrict__ scale_p,
                                                     _Float16* __restrict__ Xh,
                                                     _Float16* __restrict__ wT) {
    const int tid = threadIdx.x;
    if (blockIdx.x < 256) {
        // W[K][N] fp32 -> fp16 -> 2:4 sparsify along N (groups of 4) * scale -> wT[N][K]
        __shared__ _Float16 sT[64 * 68 + 4];   // sT[n][k], stride 68 (pad)
        const float scale = scale_p[0];
        const int k0 = (blockIdx.x & 15) * 64;
        const int n0 = (blockIdx.x >> 4) * 64;
        const int r = tid >> 4;            // 0..15
        const int c4 = (tid & 15) * 4;     // one 2:4 group = one float4
#pragma unroll
        for (int p = 0; p < 4; ++p) {
            const int k = p * 16 + r;
            float4 w4 = *(const float4*)&W[(size_t)(k0 + k) * N_TOT + n0 + c4];
            _Float16 h0 = (_Float16)w4.x, h1 = (_Float16)w4.y, h2 = (_Float16)w4.z, h3 = (_Float16)w4.w;
            float a0 = fabsf((float)h0), a1 = fabsf((float)h1), a2 = fabsf((float)h2), a3 = fabsf((float)h3);
            float lo01 = fminf(a0, a1), hi01 = fmaxf(a0, a1);
            float lo23 = fminf(a2, a3), hi23 = fmaxf(a2, a3);
            float s2 = fmaxf(fminf(hi01, hi23), fmaxf(lo01, lo23));
            sT[(c4 + 0) * 68 + k] = (_Float16)(((a0 >= s2) ? (float)h0 : 0.0f) * scale);
            sT[(c4 + 1) * 68 + k] = (_Float16)(((a1 >= s2) ? (float)h1 : 0.0f) * scale);
            sT[(c4 + 2) * 68 + k] = (_Float16)(((a2 >= s2) ? (float)h2 : 0.0f) * scale);
            sT[(c4 + 3) * 68 + k] = (_Float16)(((a3 >= s2) ? (float)h3 : 0.0f) * scale);
        }
        __syncthreads();
#pragma unroll
        for (int p = 0; p < 4; ++p) {
            const int n = p * 16 + r;
            ushort4v v = *(const ushort4v*)&sT[n * 68 + c4];
            *(ushort4v*)&wT[(size_t)(n0 + n) * K_TOT + k0 + c4] = v;
        }
    } else {
        size_t i = ((size_t)(blockIdx.x - 256) * 256 + tid) * 8;
        float4 x0 = *(const float4*)&X[i];
        float4 x1 = *(const float4*)&X[i + 4];
        f16x8 h;
        h[0] = (_Float16)x0.x; h[1] = (_Float16)x0.y; h[2] = (_Float16)x0.z; h[3] = (_Float16)x0.w;
        h[4] = (_Float16)x1.x; h[5] = (_Float16)x1.y; h[6] = (_Float16)x1.z; h[7] = (_Float16)x1.w;
        *(f16x8*)&Xh[i] = h;
    }
}

// --- Kernel 2: 256x256 tile, BK=32, 3-buffer depth-2 prefetch, ONE barrier per phase.
// 32 phases, each: {s_waitcnt vmcnt(4) [tile u retired]; s_barrier; stage tile u+2 ->
// buf (u+2)%3 (4 gl2lds); ds_read fa[8]+fb[4]; setprio(1) 32xMFMA setprio(0)}.
// Race audit: (H1) per-wave W(4) pre-barrier makes tile u globally visible post-barrier;
// (H2) stage target buf((u+2)%3)==buf((u-1)%3): its readers retired their ds_reads
// before their phase-(u-1) MFMAs (compiler lgkm waits), hence before this barrier;
// (H3) stage and this phase's reads touch different buffers. Barriers: 256 -> 32.
// Addressing/swizzle/epilogue/numerics identical to the verified round-1 kernel.
__global__ void __launch_bounds__(512, 2) gemm_bt(const _Float16* __restrict__ A,
                                                  const _Float16* __restrict__ Bt,
                                                  const float* __restrict__ bias,
                                                  float* __restrict__ C) {
    __shared__ __align__(16) _Float16 sA[3][256 * 32];   // 48 KiB
    __shared__ __align__(16) _Float16 sB[3][256 * 32];   // 48 KiB

    const int tid = threadIdx.x;
    const int id = blockIdx.x;
    const int by = id & 63;             // M tile 0..63 (by%8 = XCD; A-panel sharers co-XCD)
    const int bx = id >> 6;             // N tile 0..3
    const int wave = tid >> 6;
    const int lane = tid & 63;
    const int wm = wave >> 2;           // 0..1 -> M half (128 rows)
    const int wn = wave & 3;            // 0..3 -> N quarter (64 cols)
    const int quad = lane >> 4;
    const int l16 = lane & 15;

    // staging: 512 threads cover 128 rows x 64B per gl2lds; 2 per 256x32 tile side
    const int row0 = tid >> 2;          // 0..127
    const int s4 = tid & 3;             // 16B slot within row
    const int g = s4 ^ ((row0 >> 1) & 3);   // pre-swizzled global k-group
    const _Float16* gA = A + (size_t)(by * 256 + row0) * K_TOT + g * 8;
    const _Float16* gB = Bt + (size_t)(bx * 256 + row0) * K_TOT + g * 8;
    const int dst0 = row0 * 32 + s4 * 8;    // LDS elem off; byte off == tid*16 (DMA-legal)

    // ds_read side: slot = quad ^ ((row>>1)&3); row-dependence via l16 only (i*16 ≡ 0 mod 8)
    const int rdoff = l16 * 64 + ((quad ^ ((l16 >> 1) & 3)) << 4);   // bytes

    f32x4 acc[8][4];
#pragma unroll
    for (int i = 0; i < 8; ++i)
#pragma unroll
        for (int j = 0; j < 4; ++j)
            acc[i][j] = (f32x4){0.f, 0.f, 0.f, 0.f};
    f16x8 fa[8], fb[4];

#define STAGE(t, b) do {                                                   \
        const _Float16* sa_ = gA + (size_t)(t) * 32;                       \
        gl2lds16(sa_, &sA[b][dst0]);                                       \
        gl2lds16(sa_ + (size_t)128 * K_TOT, &sA[b][dst0 + 128 * 32]);      \
        const _Float16* sb_ = gB + (size_t)(t) * 32;                       \
        gl2lds16(sb_, &sB[b][dst0]);                                       \
        gl2lds16(sb_ + (size_t)128 * K_TOT, &sB[b][dst0 + 128 * 32]);      \
    } while (0)
#define FENCE asm volatile("" ::: "memory")

    // phase u: read tile from buf b; optionally stage tile t2 -> buf b2
#define PH(b, t2, b2, DO_STAGE, WLAST) do {                                        \
        if (WLAST) asm volatile("s_waitcnt vmcnt(0)" ::: "memory");                \
        else       asm volatile("s_waitcnt vmcnt(4)" ::: "memory");                \
        __builtin_amdgcn_sched_barrier(0);                                         \
        __builtin_amdgcn_s_barrier();                                              \
        FENCE;                                                                     \
        if (DO_STAGE) STAGE(t2, b2);                                               \
        {                                                                          \
            const char* bA_ = (const char*)&sA[b][0] + rdoff + wm * 8192;          \
            const char* bB_ = (const char*)&sB[b][0] + rdoff + wn * 4096;          \
            _Pragma("unroll")                                                      \
            for (int j = 0; j < 4; ++j) fb[j] = *(const f16x8*)(bB_ + j * 1024);   \
            _Pragma("unroll")                                                      \
            for (int i = 0; i < 8; ++i) fa[i] = *(const f16x8*)(bA_ + i * 1024);   \
        }                                                                          \
        __builtin_amdgcn_s_setprio(1);                                             \
        _Pragma("unroll")                                                          \
        for (int i = 0; i < 8; ++i) {                                              \
            _Pragma("unroll")                                                      \
            for (int j = 0; j < 4; ++j)                                            \
                acc[i][j] = __builtin_amdgcn_mfma_f32_16x16x32_f16(                \
                    fa[i], fb[j], acc[i][j], 0, 0, 0);                             \
        }                                                                          \
        __builtin_amdgcn_s_setprio(0);                                             \
    } while (0)

    // prologue: tiles 0 and 1 in flight (8 loads)
    STAGE(0, 0);
    STAGE(1, 1);

    // phases 0..29: read tile u from buf u%3, stage tile u+2 into buf (u+2)%3
    for (int it = 0; it < 10; ++it) {
        const int t = 3 * it;
        PH(0, t + 2, 2, 1, 0);
        PH(1, t + 3, 0, 1, 0);
        PH(2, t + 4, 1, 1, 0);
    }
    PH(0, 0, 0, 0, 0);   // phase 30: tile 30, no stage, W(4) retires tile 30
    PH(1, 0, 0, 0, 1);   // phase 31: tile 31, no stage, W(0)

    // epilogue (verified r1): D row = quad*4 + r (M), col = l16 (N); bias add
#pragma unroll
    for (int j = 0; j < 4; ++j) {
        const int col = bx * 256 + wn * 64 + j * 16 + l16;
        const float bj = bias[col];
#pragma unroll
        for (int mi = 0; mi < 8; ++mi) {
            const int row0o = by * 256 + wm * 128 + mi * 16 + quad * 4;
#pragma unroll
            for (int r = 0; r < 4; ++r) {
                C[(size_t)(row0o + r) * N_TOT + col] = acc[mi][j][r] + bj;
            }
        }
    }

#undef PH
#undef FENCE
#undef STAGE
}

extern "C" void kernel_launch(void* const* d_in, const int* in_sizes, int n_in,
                              void* d_out, int out_size, void* d_ws, size_t ws_size,
                              hipStream_t stream) {
    const float* x      = (const float*)d_in[0];   // [4,4096,1024] fp32
    const float* weight = (const float*)d_in[1];   // [1024,1024] fp32
    const float* bias   = (const float*)d_in[2];   // [1024] fp32
    const float* sscale = (const float*)d_in[3];   // [1] fp32
    float* out = (float*)d_out;

    _Float16* wT = (_Float16*)d_ws;                                    // 2 MiB
    _Float16* xh = (_Float16*)((char*)d_ws + (size_t)2 * 1024 * 1024); // 32 MiB

    prep_and_cast<<<256 + (M_TOT * K_TOT / 8) / 256, 256, 0, stream>>>(x, weight, sscale, xh, wT);
    gemm_bt<<<256, 512, 0, stream>>>(xh, wT, bias, out);
}